// Round 18
// baseline (160.277 us; speedup 1.0000x reference)
//
#include <hip/hip_runtime.h>
#include <hip/hip_bf16.h>
#include <stdint.h>

// GPT-2 prefill attention: B=2, S=2048, D=1024, H=16, hd=64.
// prepass (fused cvt + weight transposes) -> QKV GEMM (128^2 dbuf, direct-vT epilogue)
// -> bias tiling -> flash attn (LPT, 5 blocks/CU) -> proj GEMM.

typedef __attribute__((ext_vector_type(4))) float f32x4;
typedef __attribute__((ext_vector_type(16))) float f32x16;
typedef __attribute__((ext_vector_type(8))) short s16x8;
typedef __attribute__((ext_vector_type(4))) short s16x4;
typedef unsigned short u16;

#define LOG2E 1.4426950408889634f
#define QSCALE 0.18033688011112042f  // 0.125 * LOG2E

__device__ __forceinline__ u16 f2bf(float f) {
  unsigned w;
  asm("v_cvt_pk_bf16_f32 %0, %1, %2" : "=v"(w) : "v"(f), "v"(f));
  return (u16)w;
}
__device__ __forceinline__ unsigned cvtpk(float lo, float hi) {
  unsigned w;
  asm("v_cvt_pk_bf16_f32 %0, %1, %2" : "=v"(w) : "v"(lo), "v"(hi));
  return w;
}
__device__ __forceinline__ float bf2f(u16 h) {
  unsigned int x = ((unsigned int)h) << 16;
  return __builtin_bit_cast(float, x);
}
__device__ __forceinline__ float fexp2(float x) {   // raw v_exp_f32 (log2 domain)
  float r;
  asm("v_exp_f32 %0, %1" : "=v"(r) : "v"(x));
  return r;
}
__device__ __forceinline__ void pl32swap(unsigned& a, unsigned& b) {
  asm volatile("v_permlane32_swap_b32 %0, %1" : "+v"(a), "+v"(b));
}
__device__ __forceinline__ s16x8 frag8(unsigned a, unsigned b, unsigned c, unsigned d) {
  union { unsigned u[4]; s16x8 v; } t;
  t.u[0] = a; t.u[1] = b; t.u[2] = c; t.u[3] = d;
  return t.v;
}
__device__ __forceinline__ f32x16 mfma32(s16x8 a, s16x8 b, f32x16 c) {
  return __builtin_amdgcn_mfma_f32_32x32x16_bf16(a, b, c, 0, 0, 0);
}

__device__ __forceinline__ void gload_lds16(const u16* g, u16* lds) {
  __builtin_amdgcn_global_load_lds(
      (const __attribute__((address_space(1))) unsigned int*)g,
      (__attribute__((address_space(3))) unsigned int*)lds, 16, 0, 0);
}

// ---------------- fused prepass: cvt(hs) + transpose(c_attn_w) + transpose(c_proj_w) ----

__global__ __launch_bounds__(256) void prepass_fused(
    const float* __restrict__ hs, u16* __restrict__ hsb,
    const float* __restrict__ Wqkv, u16* __restrict__ wqkvT,
    const float* __restrict__ Wproj, u16* __restrict__ wprojT) {
  __shared__ float tile[32][33];
  const int id = blockIdx.x;
  if (id < 4096) {
    const int i = id * 256 + threadIdx.x;
    f32x4 v = *(const f32x4*)&hs[(size_t)i * 4];
    s16x4 o;
    o[0] = (short)f2bf(v[0]); o[1] = (short)f2bf(v[1]);
    o[2] = (short)f2bf(v[2]); o[3] = (short)f2bf(v[3]);
    *(s16x4*)&hsb[(size_t)i * 4] = o;
    return;
  }
  const bool qkv = (id < 7168);
  const int tw = qkv ? id - 4096 : id - 7168;
  const int nx = qkv ? 96 : 32;
  const float* W = qkv ? Wqkv : Wproj;
  u16* WT = qkv ? wqkvT : wprojT;
  const int N = qkv ? 3072 : 1024, K = 1024;
  const int n0 = (tw % nx) * 32, k0 = (tw / nx) * 32;
  const int tx = threadIdx.x & 31, ty = threadIdx.x >> 5;
#pragma unroll
  for (int i = 0; i < 32; i += 8)
    tile[ty + i][tx] = W[(size_t)(k0 + ty + i) * N + (n0 + tx)];
  __syncthreads();
#pragma unroll
  for (int i = 0; i < 32; i += 8)
    WT[(size_t)(n0 + ty + i) * K + (k0 + tx)] = f2bf(tile[tx][ty + i]);
}

// ---------------- bias tiling: packed triangular bf16 table, 32x32 C/D layout ----------
// 1024 blocks x 2 cells (128 threads/cell). *LOG2E folded, causal mask folded as -inf.

__global__ __launch_bounds__(256) void bias_tile(const float* __restrict__ B,
                                                 u16* __restrict__ T) {
  const int cell = blockIdx.x * 2 + (threadIdx.x >> 7);
  const int kt = cell & 31, q32 = cell >> 5;
  if (kt > (q32 >> 1)) return;
  const int tid7 = threadIdx.x & 127;
  const int t = tid7 >> 6, lane = tid7 & 63;
  const int hh = q32 >> 1;
  const size_t boff = (size_t)(hh + (q32 & 1)) * (hh + 1);
  const int q = q32 * 32 + (lane & 31);
  const int kb = kt * 64 + t * 32 + 4 * (lane >> 5);
  u16 vv[16];
#pragma unroll
  for (int r = 0; r < 16; r++) {
    const int k = kb + (r & 3) + 8 * (r >> 2);
    vv[r] = (k <= q) ? f2bf(B[(size_t)q * 2048 + k] * LOG2E) : (u16)0xFF80;
  }
  u16* dst = T + (boff + kt) * 2048 + t * 1024 + (size_t)lane * 16;
  *(s16x8*)dst = *(s16x8*)&vv[0];
  *(s16x8*)(dst + 8) = *(s16x8*)&vv[8];
}

// ---------------- GEMM: C[M][N] = A[M][K] * BT[N][K]^T + bias ----------------
// 128^2 tile, BK=32, 4 waves, double-buffered (round-8/11 verified).
// MODE 0 epilogue: q scaled bf16; k fp32 out + bf16 ws; v fp32 out + DIRECT vT bf16.

template <int MODE>
__global__ __launch_bounds__(256) void gemm_bt(
    const u16* __restrict__ A, const u16* __restrict__ BT,
    const float* __restrict__ bias, float* __restrict__ outF,
    u16* __restrict__ q_ws, u16* __restrict__ k_ws, u16* __restrict__ vT_ws,
    int M, int N, int K) {
  __shared__ u16 As[2][128 * 32];
  __shared__ u16 Bs[2][128 * 32];
  const int nwg = gridDim.x * gridDim.y;
  int flat = blockIdx.y * gridDim.x + blockIdx.x;
  flat = (flat & 7) * (nwg >> 3) + (flat >> 3);
  const int m0 = (flat / gridDim.x) * 128, n0 = (flat % gridDim.x) * 128;
  const int tid = threadIdx.x;
  const int wid = tid >> 6, lane = tid & 63;
  const int c = lane & 15, hi = lane >> 4;
  const int wm = wid >> 1, wn = wid & 1;
  const int srow = lane >> 2;
  const int skp = (lane & 3) * 8;

  f32x4 acc[4][4] = {};

#define STG(SLOT, K0)                                                         \
  {                                                                           \
    _Pragma("unroll")                                                         \
    for (int t = 0; t < 2; t++) {                                             \
      const int rowl = wid * 32 + t * 16;                                     \
      gload_lds16(&A[(size_t)(m0 + rowl + srow) * K + (K0) + skp],            \
                  &As[SLOT][rowl * 32]);                                      \
      gload_lds16(&BT[(size_t)(n0 + rowl + srow) * K + (K0) + skp],           \
                  &Bs[SLOT][rowl * 32]);                                      \
    }                                                                         \
  }

  STG(0, 0);
  __syncthreads();

  int bufi = 0;
  for (int k0 = 0; k0 < K; k0 += 32) {
    if (k0 + 32 < K) {
      if (bufi) { STG(0, k0 + 32); } else { STG(1, k0 + 32); }
    }
    s16x8 af[4], bfr[4];
#pragma unroll
    for (int i = 0; i < 4; i++)
      af[i] = *(const s16x8*)&As[bufi][(wm * 64 + i * 16 + c) * 32 + hi * 8];
#pragma unroll
    for (int i = 0; i < 4; i++)
      bfr[i] = *(const s16x8*)&Bs[bufi][(wn * 64 + i * 16 + c) * 32 + hi * 8];
    __builtin_amdgcn_s_setprio(1);
#pragma unroll
    for (int i = 0; i < 4; i++)
#pragma unroll
      for (int j = 0; j < 4; j++)
        acc[i][j] = __builtin_amdgcn_mfma_f32_16x16x32_bf16(af[i], bfr[j], acc[i][j], 0, 0, 0);
    __builtin_amdgcn_s_setprio(0);
    __syncthreads();
    bufi ^= 1;
  }
#undef STG

  if (MODE == 1) {
#pragma unroll
    for (int i = 0; i < 4; i++) {
#pragma unroll
      for (int j = 0; j < 4; j++) {
        const int col = n0 + wn * 64 + j * 16 + c;
        const int rb = m0 + wm * 64 + i * 16 + hi * 4;
        const float bv = bias[col];
#pragma unroll
        for (int u = 0; u < 4; u++)
          outF[(size_t)(rb + u) * N + col] = acc[i][j][u] + bv;
      }
    }
  } else {
    const int which = n0 >> 10;    // block-uniform: 0=q 1=k 2=v
#pragma unroll
    for (int i = 0; i < 4; i++) {
#pragma unroll
      for (int j = 0; j < 4; j++) {
        const int col = n0 + wn * 64 + j * 16 + c;
        const int rb = m0 + wm * 64 + i * 16 + hi * 4;
        const float bv = bias[col];
        const int h = (col >> 6) & 15, d = col & 63;
        if (which == 2) {
          // fp32 out (coalesced per hi-group) + direct vT bf16 (8B per thread)
          const int b = rb >> 11, s0 = rb & 2047;
#pragma unroll
          for (int u = 0; u < 4; u++)
            outF[8388608u + (size_t)(b * 16 + h) * 131072u + (size_t)(s0 + u) * 64 + d] =
                acc[i][j][u] + bv;
          uint2 w;
          w.x = cvtpk(acc[i][j][0] + bv, acc[i][j][1] + bv);
          w.y = cvtpk(acc[i][j][2] + bv, acc[i][j][3] + bv);
          *(uint2*)&vT_ws[(size_t)(b * 16 + h) * 131072u + (size_t)d * 2048 + s0] = w;
        } else {
#pragma unroll
          for (int u = 0; u < 4; u++) {
            const int r = rb + u;
            const int b = r >> 11, s = r & 2047;
            const size_t idx = (size_t)(b * 16 + h) * 131072u + (size_t)s * 64 + d;
            const float v = acc[i][j][u] + bv;
            if (which == 0) {
              q_ws[idx] = f2bf(v * QSCALE);   // fold 1/sqrt(hd) * LOG2E
            } else {
              outF[4194304u + idx] = v;
              k_ws[idx] = f2bf(v);
            }
          }
        }
      }
    }
  }
}

// ---------------- fused causal attention ----------------
// 1024 blocks, LPT dispatch; 4 waves = (pq q-subtile, par k-half); swapped QK^T,
// in-register softmax, bf16 bias C-init (prefetched), reg-q-space k-half merge.
// __launch_bounds__(256, 5): 5 blocks/CU (5 x 32KB LDS = 160KB pool exactly).

__global__ __launch_bounds__(256, 5) void attn_fused(
    const u16* __restrict__ q_ws, const u16* __restrict__ k_ws,
    const u16* __restrict__ vT_ws, const u16* __restrict__ biasT,
    u16* __restrict__ ctx) {
  __shared__ u16 Ks[2][64 * 64];
  __shared__ u16 Vs[2][64 * 64];

  const int id = blockIdx.x;
  const int bh = (id & 7) * 4 + ((id >> 3) & 3);
  const int qblk = 31 - (id >> 5);               // LPT: longest blocks dispatch first

  const int wid = threadIdx.x >> 6, lane = threadIdx.x & 63;
  const int pq = wid >> 1, par = wid & 1;
  const int l31 = lane & 31, hi5 = lane >> 5;
  const int qrow0 = qblk * 64 + pq * 32;

  const u16* qh = q_ws + (size_t)bh * 131072u;
  const u16* kh = k_ws + (size_t)bh * 131072u;
  const u16* vh = vT_ws + (size_t)bh * 131072u;

  s16x8 qf[4];
#pragma unroll
  for (int s = 0; s < 4; s++)
    qf[s] = *(const s16x8*)&qh[(size_t)(qrow0 + l31) * 64 + s * 16 + hi5 * 8];

  const int q32 = qblk * 2 + pq;
  const int hh = q32 >> 1;
  const size_t boff = (size_t)(hh + (q32 & 1)) * (hh + 1);
  const u16* bbase = biasT + boff * 2048 + (size_t)par * 1024 + (size_t)lane * 16;

  const int sl_r = lane >> 3, sl_c = lane & 7;

  f32x16 o0 = {}, o1 = {};
  float mrow = -1e30f, lpart = 0.f;

#define STAGE(BUF, N0)                                                        \
  {                                                                           \
    _Pragma("unroll")                                                         \
    for (int t = 0; t < 2; t++) {                                             \
      const int rb = wid * 16 + t * 8;                                        \
      const int r = rb + sl_r;                                                \
      gload_lds16(&kh[(size_t)((N0) + r) * 64 + ((sl_c ^ (r & 7)) * 8)],      \
                  &Ks[BUF][rb * 64]);                                         \
      gload_lds16(&vh[(size_t)r * 2048 + (N0) + ((sl_c ^ (r & 7)) * 8)],      \
                  &Vs[BUF][rb * 64]);                                         \
    }                                                                         \
  }

  STAGE(0, 0);
  __syncthreads();

  int buf = 0;
  const int nkt = qblk + 1;
  const int swz = l31 & 7;
  const int arow = par * 32 + l31;

  s16x8 bc0 = *(const s16x8*)(bbase);
  s16x8 bc1 = *(const s16x8*)(bbase + 8);

  for (int kt = 0; kt < nkt; ++kt) {
    if (kt + 1 < nkt) {
      if (buf) { STAGE(0, kt * 64 + 64); } else { STAGE(1, kt * 64 + 64); }
    }
    const u16* btn = bbase + (size_t)((kt + 1 < nkt) ? kt + 1 : kt) * 2048;
    const s16x8 bn0 = *(const s16x8*)(btn);
    const s16x8 bn1 = *(const s16x8*)(btn + 8);

    f32x16 s0;
#pragma unroll
    for (int r = 0; r < 8; r++) {
      s0[r] = bf2f((u16)bc0[r]);
      s0[r + 8] = bf2f((u16)bc1[r]);
    }

    const u16* ksb = &Ks[buf][0];
    __builtin_amdgcn_s_setprio(1);
#pragma unroll
    for (int s = 0; s < 4; s++) {
      const int chq = ((s * 2 + hi5) ^ swz) * 8;
      const s16x8 a0 = *(const s16x8*)&ksb[arow * 64 + chq];
      s0 = mfma32(a0, qf[s], s0);
    }
    __builtin_amdgcn_s_setprio(0);

    float t0 = fmaxf(fmaxf(s0[0], s0[1]), fmaxf(s0[2], s0[3]));
    float t1 = fmaxf(fmaxf(s0[4], s0[5]), fmaxf(s0[6], s0[7]));
    float t2 = fmaxf(fmaxf(s0[8], s0[9]), fmaxf(s0[10], s0[11]));
    float t3 = fmaxf(fmaxf(s0[12], s0[13]), fmaxf(s0[14], s0[15]));
    float tm = fmaxf(fmaxf(t0, t1), fmaxf(t2, t3));
    tm = fmaxf(tm, __shfl_xor(tm, 32));

    if (__any(tm > mrow + 8.f)) {
      const float nm = fmaxf(mrow, tm);
      const float al = fexp2(mrow - nm);
      mrow = nm;
      lpart *= al;
#pragma unroll
      for (int r = 0; r < 16; r++) { o0[r] *= al; o1[r] *= al; }
    }

    float a0s = 0.f, a1s = 0.f;
#pragma unroll
    for (int r = 0; r < 8; r++) {
      s0[r] = fexp2(s0[r] - mrow);       a0s += s0[r];
      s0[r + 8] = fexp2(s0[r + 8] - mrow); a1s += s0[r + 8];
    }
    lpart += a0s + a1s;

    unsigned wv0 = cvtpk(s0[0], s0[1]),   wv1 = cvtpk(s0[2], s0[3]);
    unsigned wv2 = cvtpk(s0[4], s0[5]),   wv3 = cvtpk(s0[6], s0[7]);
    unsigned wv4 = cvtpk(s0[8], s0[9]),   wv5 = cvtpk(s0[10], s0[11]);
    unsigned wv6 = cvtpk(s0[12], s0[13]), wv7 = cvtpk(s0[14], s0[15]);
    pl32swap(wv0, wv2); pl32swap(wv1, wv3);
    pl32swap(wv4, wv6); pl32swap(wv5, wv7);

    const u16* vsb = &Vs[buf][0];
    __builtin_amdgcn_s_setprio(1);
#pragma unroll
    for (int hf = 0; hf < 2; hf++) {
      const s16x8 pa = hf ? frag8(wv4, wv5, wv6, wv7) : frag8(wv0, wv1, wv2, wv3);
      const int s = par * 2 + hf;
      const int chv = ((s * 2 + hi5) ^ swz) * 8;
      const s16x8 v0 = *(const s16x8*)&vsb[l31 * 64 + chv];
      const s16x8 v1 = *(const s16x8*)&vsb[(32 + l31) * 64 + chv];
      o0 = mfma32(pa, v0, o0);
      o1 = mfma32(pa, v1, o1);
    }
    __builtin_amdgcn_s_setprio(0);

    __syncthreads();
    buf ^= 1;
    bc0 = bn0; bc1 = bn1;
  }
#undef STAGE

  lpart += __shfl_xor(lpart, 32);

  float* obuf = (float*)&Ks[0][0];     // [32 reg][128 slot] f32 = 16KB
  float2* mlb = (float2*)&Vs[0][0];    // [(par*2+pq)*64 + q] -> (m, l)

  __syncthreads();
  if (hi5 == 0) mlb[(par * 2 + pq) * 64 + l31] = make_float2(mrow, lpart);
  if (par == 1) {
    const int slot = pq * 64 + lane;
#pragma unroll
    for (int r = 0; r < 16; r++) {
      obuf[r * 128 + slot] = o0[r];
      obuf[(16 + r) * 128 + slot] = o1[r];
    }
  }
  __syncthreads();
  if (par == 0) {
    const int slot = pq * 64 + lane;
    const int b = bh >> 4, h = bh & 15;
#pragma unroll
    for (int r = 0; r < 16; r++) {
      const int qloc = (r & 3) + 8 * (r >> 2) + 4 * hi5;
      const float2 Aml = mlb[pq * 64 + qloc];
      const float2 Bml = mlb[(2 + pq) * 64 + qloc];
      const float mm = fmaxf(Aml.x, Bml.x);
      const float fa = fexp2(Aml.x - mm), fb = fexp2(Bml.x - mm);
      const float inv = __builtin_amdgcn_rcpf(Aml.y * fa + Bml.y * fb);
      const float om0 = (o0[r] * fa + obuf[r * 128 + slot] * fb) * inv;
      const float om1 = (o1[r] * fa + obuf[(16 + r) * 128 + slot] * fb) * inv;
      const int tok = b * 2048 + qrow0 + qloc;
      ctx[(size_t)tok * 1024 + h * 64 + l31] = f2bf(om0);
      ctx[(size_t)tok * 1024 + h * 64 + 32 + l31] = f2bf(om1);
    }
  }
}

// ---------------- launch ----------------

extern "C" void kernel_launch(void* const* d_in, const int* in_sizes, int n_in,
                              void* d_out, int out_size, void* d_ws, size_t ws_size,
                              hipStream_t stream) {
  const float* hs        = (const float*)d_in[0];  // [2,2048,1024]
  const float* c_attn_w  = (const float*)d_in[1];  // [1024,3072]
  const float* c_attn_b  = (const float*)d_in[2];  // [3072]
  const float* attn_bias = (const float*)d_in[3];  // [2048,2048]
  const float* c_proj_w  = (const float*)d_in[4];  // [1024,1024]
  const float* c_proj_b  = (const float*)d_in[5];  // [1024]
  float* out = (float*)d_out;  // out(4M) | k(4M) | v(4M)

  uint8_t* ws = (uint8_t*)d_ws;
  u16* hsb    = (u16*)(ws + 0);           // 8MB [4096][1024] bf16 (reused for biasT, 4.3MB)
  u16* wqkvT  = (u16*)(ws + 8388608u);    // 6MB [3072][1024] bf16
  u16* wprojT = (u16*)(ws + 14680064u);   // 2MB [1024][1024] bf16
  u16* q_ws   = (u16*)(ws + 16777216u);   // 8MB [B,H,S,hd] bf16 (q * QSCALE)
  u16* k_ws   = (u16*)(ws + 25165824u);   // 8MB [B,H,S,hd] bf16
  u16* vT_ws  = (u16*)(ws + 33554432u);   // 8MB [B,H,hd,S] bf16 (written by gemm<0>)
  u16* ctx    = (u16*)(ws + 41943040u);   // 8MB [4096][1024] bf16
  u16* biasT  = hsb;                      // overlays hsb after gemm_bt<0>

  prepass_fused<<<8192, 256, 0, stream>>>(hs, hsb, c_attn_w, wqkvT, c_proj_w, wprojT);

  gemm_bt<0><<<dim3(24, 32), 256, 0, stream>>>(hsb, wqkvT, c_attn_b, out,
                                               q_ws, k_ws, vT_ws, 4096, 3072, 1024);

  bias_tile<<<1024, 256, 0, stream>>>(attn_bias, biasT);

  attn_fused<<<dim3(1024), 256, 0, stream>>>(q_ws, k_ws, vT_ws, biasT, ctx);

  gemm_bt<1><<<dim3(8, 32), 256, 0, stream>>>(ctx, wprojT, c_proj_b, out,
                                              (u16*)nullptr, (u16*)nullptr, (u16*)nullptr,
                                              4096, 1024, 1024);
}

// Round 19
// 121.191 us; speedup vs baseline: 1.3225x; 1.3225x over previous
//
#include <hip/hip_runtime.h>
#include <hip/hip_bf16.h>
#include <stdint.h>

// GPT-2 prefill attention: B=2, S=2048, D=1024, H=16, hd=64.
// prepass (fused cvt + weight transposes) -> QKV GEMM (128^2 dbuf, direct-vT epilogue)
// -> bias tiling -> flash attn (LPT, 4 blocks/CU) -> proj GEMM.
// [round-14/17 best-known config, twice reproduced at ~121.3 us]

typedef __attribute__((ext_vector_type(4))) float f32x4;
typedef __attribute__((ext_vector_type(16))) float f32x16;
typedef __attribute__((ext_vector_type(8))) short s16x8;
typedef __attribute__((ext_vector_type(4))) short s16x4;
typedef unsigned short u16;

#define LOG2E 1.4426950408889634f
#define QSCALE 0.18033688011112042f  // 0.125 * LOG2E

__device__ __forceinline__ u16 f2bf(float f) {
  unsigned w;
  asm("v_cvt_pk_bf16_f32 %0, %1, %2" : "=v"(w) : "v"(f), "v"(f));
  return (u16)w;
}
__device__ __forceinline__ unsigned cvtpk(float lo, float hi) {
  unsigned w;
  asm("v_cvt_pk_bf16_f32 %0, %1, %2" : "=v"(w) : "v"(lo), "v"(hi));
  return w;
}
__device__ __forceinline__ float bf2f(u16 h) {
  unsigned int x = ((unsigned int)h) << 16;
  return __builtin_bit_cast(float, x);
}
__device__ __forceinline__ float fexp2(float x) {   // raw v_exp_f32 (log2 domain)
  float r;
  asm("v_exp_f32 %0, %1" : "=v"(r) : "v"(x));
  return r;
}
__device__ __forceinline__ void pl32swap(unsigned& a, unsigned& b) {
  asm volatile("v_permlane32_swap_b32 %0, %1" : "+v"(a), "+v"(b));
}
__device__ __forceinline__ s16x8 frag8(unsigned a, unsigned b, unsigned c, unsigned d) {
  union { unsigned u[4]; s16x8 v; } t;
  t.u[0] = a; t.u[1] = b; t.u[2] = c; t.u[3] = d;
  return t.v;
}
__device__ __forceinline__ f32x16 mfma32(s16x8 a, s16x8 b, f32x16 c) {
  return __builtin_amdgcn_mfma_f32_32x32x16_bf16(a, b, c, 0, 0, 0);
}

__device__ __forceinline__ void gload_lds16(const u16* g, u16* lds) {
  __builtin_amdgcn_global_load_lds(
      (const __attribute__((address_space(1))) unsigned int*)g,
      (__attribute__((address_space(3))) unsigned int*)lds, 16, 0, 0);
}

// ---------------- fused prepass: cvt(hs) + transpose(c_attn_w) + transpose(c_proj_w) ----

__global__ __launch_bounds__(256) void prepass_fused(
    const float* __restrict__ hs, u16* __restrict__ hsb,
    const float* __restrict__ Wqkv, u16* __restrict__ wqkvT,
    const float* __restrict__ Wproj, u16* __restrict__ wprojT) {
  __shared__ float tile[32][33];
  const int id = blockIdx.x;
  if (id < 4096) {
    const int i = id * 256 + threadIdx.x;
    f32x4 v = *(const f32x4*)&hs[(size_t)i * 4];
    s16x4 o;
    o[0] = (short)f2bf(v[0]); o[1] = (short)f2bf(v[1]);
    o[2] = (short)f2bf(v[2]); o[3] = (short)f2bf(v[3]);
    *(s16x4*)&hsb[(size_t)i * 4] = o;
    return;
  }
  const bool qkv = (id < 7168);
  const int tw = qkv ? id - 4096 : id - 7168;
  const int nx = qkv ? 96 : 32;
  const float* W = qkv ? Wqkv : Wproj;
  u16* WT = qkv ? wqkvT : wprojT;
  const int N = qkv ? 3072 : 1024, K = 1024;
  const int n0 = (tw % nx) * 32, k0 = (tw / nx) * 32;
  const int tx = threadIdx.x & 31, ty = threadIdx.x >> 5;
#pragma unroll
  for (int i = 0; i < 32; i += 8)
    tile[ty + i][tx] = W[(size_t)(k0 + ty + i) * N + (n0 + tx)];
  __syncthreads();
#pragma unroll
  for (int i = 0; i < 32; i += 8)
    WT[(size_t)(n0 + ty + i) * K + (k0 + tx)] = f2bf(tile[tx][ty + i]);
}

// ---------------- bias tiling: packed triangular bf16 table, 32x32 C/D layout ----------
// 1024 blocks x 2 cells (128 threads/cell). *LOG2E folded, causal mask folded as -inf.

__global__ __launch_bounds__(256) void bias_tile(const float* __restrict__ B,
                                                 u16* __restrict__ T) {
  const int cell = blockIdx.x * 2 + (threadIdx.x >> 7);
  const int kt = cell & 31, q32 = cell >> 5;
  if (kt > (q32 >> 1)) return;
  const int tid7 = threadIdx.x & 127;
  const int t = tid7 >> 6, lane = tid7 & 63;
  const int hh = q32 >> 1;
  const size_t boff = (size_t)(hh + (q32 & 1)) * (hh + 1);
  const int q = q32 * 32 + (lane & 31);
  const int kb = kt * 64 + t * 32 + 4 * (lane >> 5);
  u16 vv[16];
#pragma unroll
  for (int r = 0; r < 16; r++) {
    const int k = kb + (r & 3) + 8 * (r >> 2);
    vv[r] = (k <= q) ? f2bf(B[(size_t)q * 2048 + k] * LOG2E) : (u16)0xFF80;
  }
  u16* dst = T + (boff + kt) * 2048 + t * 1024 + (size_t)lane * 16;
  *(s16x8*)dst = *(s16x8*)&vv[0];
  *(s16x8*)(dst + 8) = *(s16x8*)&vv[8];
}

// ---------------- GEMM: C[M][N] = A[M][K] * BT[N][K]^T + bias ----------------
// 128^2 tile, BK=32, 4 waves, double-buffered (round-8/11 verified).
// MODE 0 epilogue: q scaled bf16; k fp32 out + bf16 ws; v fp32 out + DIRECT vT bf16.

template <int MODE>
__global__ __launch_bounds__(256) void gemm_bt(
    const u16* __restrict__ A, const u16* __restrict__ BT,
    const float* __restrict__ bias, float* __restrict__ outF,
    u16* __restrict__ q_ws, u16* __restrict__ k_ws, u16* __restrict__ vT_ws,
    int M, int N, int K) {
  __shared__ u16 As[2][128 * 32];
  __shared__ u16 Bs[2][128 * 32];
  const int nwg = gridDim.x * gridDim.y;
  int flat = blockIdx.y * gridDim.x + blockIdx.x;
  flat = (flat & 7) * (nwg >> 3) + (flat >> 3);
  const int m0 = (flat / gridDim.x) * 128, n0 = (flat % gridDim.x) * 128;
  const int tid = threadIdx.x;
  const int wid = tid >> 6, lane = tid & 63;
  const int c = lane & 15, hi = lane >> 4;
  const int wm = wid >> 1, wn = wid & 1;
  const int srow = lane >> 2;
  const int skp = (lane & 3) * 8;

  f32x4 acc[4][4] = {};

#define STG(SLOT, K0)                                                         \
  {                                                                           \
    _Pragma("unroll")                                                         \
    for (int t = 0; t < 2; t++) {                                             \
      const int rowl = wid * 32 + t * 16;                                     \
      gload_lds16(&A[(size_t)(m0 + rowl + srow) * K + (K0) + skp],            \
                  &As[SLOT][rowl * 32]);                                      \
      gload_lds16(&BT[(size_t)(n0 + rowl + srow) * K + (K0) + skp],           \
                  &Bs[SLOT][rowl * 32]);                                      \
    }                                                                         \
  }

  STG(0, 0);
  __syncthreads();

  int bufi = 0;
  for (int k0 = 0; k0 < K; k0 += 32) {
    if (k0 + 32 < K) {
      if (bufi) { STG(0, k0 + 32); } else { STG(1, k0 + 32); }
    }
    s16x8 af[4], bfr[4];
#pragma unroll
    for (int i = 0; i < 4; i++)
      af[i] = *(const s16x8*)&As[bufi][(wm * 64 + i * 16 + c) * 32 + hi * 8];
#pragma unroll
    for (int i = 0; i < 4; i++)
      bfr[i] = *(const s16x8*)&Bs[bufi][(wn * 64 + i * 16 + c) * 32 + hi * 8];
    __builtin_amdgcn_s_setprio(1);
#pragma unroll
    for (int i = 0; i < 4; i++)
#pragma unroll
      for (int j = 0; j < 4; j++)
        acc[i][j] = __builtin_amdgcn_mfma_f32_16x16x32_bf16(af[i], bfr[j], acc[i][j], 0, 0, 0);
    __builtin_amdgcn_s_setprio(0);
    __syncthreads();
    bufi ^= 1;
  }
#undef STG

  if (MODE == 1) {
#pragma unroll
    for (int i = 0; i < 4; i++) {
#pragma unroll
      for (int j = 0; j < 4; j++) {
        const int col = n0 + wn * 64 + j * 16 + c;
        const int rb = m0 + wm * 64 + i * 16 + hi * 4;
        const float bv = bias[col];
#pragma unroll
        for (int u = 0; u < 4; u++)
          outF[(size_t)(rb + u) * N + col] = acc[i][j][u] + bv;
      }
    }
  } else {
    const int which = n0 >> 10;    // block-uniform: 0=q 1=k 2=v
#pragma unroll
    for (int i = 0; i < 4; i++) {
#pragma unroll
      for (int j = 0; j < 4; j++) {
        const int col = n0 + wn * 64 + j * 16 + c;
        const int rb = m0 + wm * 64 + i * 16 + hi * 4;
        const float bv = bias[col];
        const int h = (col >> 6) & 15, d = col & 63;
        if (which == 2) {
          // fp32 out (coalesced per hi-group) + direct vT bf16 (8B per thread)
          const int b = rb >> 11, s0 = rb & 2047;
#pragma unroll
          for (int u = 0; u < 4; u++)
            outF[8388608u + (size_t)(b * 16 + h) * 131072u + (size_t)(s0 + u) * 64 + d] =
                acc[i][j][u] + bv;
          uint2 w;
          w.x = cvtpk(acc[i][j][0] + bv, acc[i][j][1] + bv);
          w.y = cvtpk(acc[i][j][2] + bv, acc[i][j][3] + bv);
          *(uint2*)&vT_ws[(size_t)(b * 16 + h) * 131072u + (size_t)d * 2048 + s0] = w;
        } else {
#pragma unroll
          for (int u = 0; u < 4; u++) {
            const int r = rb + u;
            const int b = r >> 11, s = r & 2047;
            const size_t idx = (size_t)(b * 16 + h) * 131072u + (size_t)s * 64 + d;
            const float v = acc[i][j][u] + bv;
            if (which == 0) {
              q_ws[idx] = f2bf(v * QSCALE);   // fold 1/sqrt(hd) * LOG2E
            } else {
              outF[4194304u + idx] = v;
              k_ws[idx] = f2bf(v);
            }
          }
        }
      }
    }
  }
}

// ---------------- fused causal attention (round-11, verified) ----------------
// 1024 blocks, LPT dispatch; 4 waves = (pq q-subtile, par k-half); swapped QK^T,
// in-register softmax, bf16 bias C-init (prefetched), reg-q-space k-half merge.

__global__ __launch_bounds__(256, 4) void attn_fused(
    const u16* __restrict__ q_ws, const u16* __restrict__ k_ws,
    const u16* __restrict__ vT_ws, const u16* __restrict__ biasT,
    u16* __restrict__ ctx) {
  __shared__ u16 Ks[2][64 * 64];
  __shared__ u16 Vs[2][64 * 64];

  const int id = blockIdx.x;
  const int bh = (id & 7) * 4 + ((id >> 3) & 3);
  const int qblk = 31 - (id >> 5);               // LPT: longest blocks dispatch first

  const int wid = threadIdx.x >> 6, lane = threadIdx.x & 63;
  const int pq = wid >> 1, par = wid & 1;
  const int l31 = lane & 31, hi5 = lane >> 5;
  const int qrow0 = qblk * 64 + pq * 32;

  const u16* qh = q_ws + (size_t)bh * 131072u;
  const u16* kh = k_ws + (size_t)bh * 131072u;
  const u16* vh = vT_ws + (size_t)bh * 131072u;

  s16x8 qf[4];
#pragma unroll
  for (int s = 0; s < 4; s++)
    qf[s] = *(const s16x8*)&qh[(size_t)(qrow0 + l31) * 64 + s * 16 + hi5 * 8];

  const int q32 = qblk * 2 + pq;
  const int hh = q32 >> 1;
  const size_t boff = (size_t)(hh + (q32 & 1)) * (hh + 1);
  const u16* bbase = biasT + boff * 2048 + (size_t)par * 1024 + (size_t)lane * 16;

  const int sl_r = lane >> 3, sl_c = lane & 7;

  f32x16 o0 = {}, o1 = {};
  float mrow = -1e30f, lpart = 0.f;

#define STAGE(BUF, N0)                                                        \
  {                                                                           \
    _Pragma("unroll")                                                         \
    for (int t = 0; t < 2; t++) {                                             \
      const int rb = wid * 16 + t * 8;                                        \
      const int r = rb + sl_r;                                                \
      gload_lds16(&kh[(size_t)((N0) + r) * 64 + ((sl_c ^ (r & 7)) * 8)],      \
                  &Ks[BUF][rb * 64]);                                         \
      gload_lds16(&vh[(size_t)r * 2048 + (N0) + ((sl_c ^ (r & 7)) * 8)],      \
                  &Vs[BUF][rb * 64]);                                         \
    }                                                                         \
  }

  STAGE(0, 0);
  __syncthreads();

  int buf = 0;
  const int nkt = qblk + 1;
  const int swz = l31 & 7;
  const int arow = par * 32 + l31;

  s16x8 bc0 = *(const s16x8*)(bbase);
  s16x8 bc1 = *(const s16x8*)(bbase + 8);

  for (int kt = 0; kt < nkt; ++kt) {
    if (kt + 1 < nkt) {
      if (buf) { STAGE(0, kt * 64 + 64); } else { STAGE(1, kt * 64 + 64); }
    }
    const u16* btn = bbase + (size_t)((kt + 1 < nkt) ? kt + 1 : kt) * 2048;
    const s16x8 bn0 = *(const s16x8*)(btn);
    const s16x8 bn1 = *(const s16x8*)(btn + 8);

    f32x16 s0;
#pragma unroll
    for (int r = 0; r < 8; r++) {
      s0[r] = bf2f((u16)bc0[r]);
      s0[r + 8] = bf2f((u16)bc1[r]);
    }

    const u16* ksb = &Ks[buf][0];
    __builtin_amdgcn_s_setprio(1);
#pragma unroll
    for (int s = 0; s < 4; s++) {
      const int chq = ((s * 2 + hi5) ^ swz) * 8;
      const s16x8 a0 = *(const s16x8*)&ksb[arow * 64 + chq];
      s0 = mfma32(a0, qf[s], s0);
    }
    __builtin_amdgcn_s_setprio(0);

    float t0 = fmaxf(fmaxf(s0[0], s0[1]), fmaxf(s0[2], s0[3]));
    float t1 = fmaxf(fmaxf(s0[4], s0[5]), fmaxf(s0[6], s0[7]));
    float t2 = fmaxf(fmaxf(s0[8], s0[9]), fmaxf(s0[10], s0[11]));
    float t3 = fmaxf(fmaxf(s0[12], s0[13]), fmaxf(s0[14], s0[15]));
    float tm = fmaxf(fmaxf(t0, t1), fmaxf(t2, t3));
    tm = fmaxf(tm, __shfl_xor(tm, 32));

    if (__any(tm > mrow + 8.f)) {
      const float nm = fmaxf(mrow, tm);
      const float al = fexp2(mrow - nm);
      mrow = nm;
      lpart *= al;
#pragma unroll
      for (int r = 0; r < 16; r++) { o0[r] *= al; o1[r] *= al; }
    }

    float a0s = 0.f, a1s = 0.f;
#pragma unroll
    for (int r = 0; r < 8; r++) {
      s0[r] = fexp2(s0[r] - mrow);       a0s += s0[r];
      s0[r + 8] = fexp2(s0[r + 8] - mrow); a1s += s0[r + 8];
    }
    lpart += a0s + a1s;

    unsigned wv0 = cvtpk(s0[0], s0[1]),   wv1 = cvtpk(s0[2], s0[3]);
    unsigned wv2 = cvtpk(s0[4], s0[5]),   wv3 = cvtpk(s0[6], s0[7]);
    unsigned wv4 = cvtpk(s0[8], s0[9]),   wv5 = cvtpk(s0[10], s0[11]);
    unsigned wv6 = cvtpk(s0[12], s0[13]), wv7 = cvtpk(s0[14], s0[15]);
    pl32swap(wv0, wv2); pl32swap(wv1, wv3);
    pl32swap(wv4, wv6); pl32swap(wv5, wv7);

    const u16* vsb = &Vs[buf][0];
    __builtin_amdgcn_s_setprio(1);
#pragma unroll
    for (int hf = 0; hf < 2; hf++) {
      const s16x8 pa = hf ? frag8(wv4, wv5, wv6, wv7) : frag8(wv0, wv1, wv2, wv3);
      const int s = par * 2 + hf;
      const int chv = ((s * 2 + hi5) ^ swz) * 8;
      const s16x8 v0 = *(const s16x8*)&vsb[l31 * 64 + chv];
      const s16x8 v1 = *(const s16x8*)&vsb[(32 + l31) * 64 + chv];
      o0 = mfma32(pa, v0, o0);
      o1 = mfma32(pa, v1, o1);
    }
    __builtin_amdgcn_s_setprio(0);

    __syncthreads();
    buf ^= 1;
    bc0 = bn0; bc1 = bn1;
  }
#undef STAGE

  lpart += __shfl_xor(lpart, 32);

  float* obuf = (float*)&Ks[0][0];     // [32 reg][128 slot] f32 = 16KB
  float2* mlb = (float2*)&Vs[0][0];    // [(par*2+pq)*64 + q] -> (m, l)

  __syncthreads();
  if (hi5 == 0) mlb[(par * 2 + pq) * 64 + l31] = make_float2(mrow, lpart);
  if (par == 1) {
    const int slot = pq * 64 + lane;
#pragma unroll
    for (int r = 0; r < 16; r++) {
      obuf[r * 128 + slot] = o0[r];
      obuf[(16 + r) * 128 + slot] = o1[r];
    }
  }
  __syncthreads();
  if (par == 0) {
    const int slot = pq * 64 + lane;
    const int b = bh >> 4, h = bh & 15;
#pragma unroll
    for (int r = 0; r < 16; r++) {
      const int qloc = (r & 3) + 8 * (r >> 2) + 4 * hi5;
      const float2 Aml = mlb[pq * 64 + qloc];
      const float2 Bml = mlb[(2 + pq) * 64 + qloc];
      const float mm = fmaxf(Aml.x, Bml.x);
      const float fa = fexp2(Aml.x - mm), fb = fexp2(Bml.x - mm);
      const float inv = __builtin_amdgcn_rcpf(Aml.y * fa + Bml.y * fb);
      const float om0 = (o0[r] * fa + obuf[r * 128 + slot] * fb) * inv;
      const float om1 = (o1[r] * fa + obuf[(16 + r) * 128 + slot] * fb) * inv;
      const int tok = b * 2048 + qrow0 + qloc;
      ctx[(size_t)tok * 1024 + h * 64 + l31] = f2bf(om0);
      ctx[(size_t)tok * 1024 + h * 64 + 32 + l31] = f2bf(om1);
    }
  }
}

// ---------------- launch ----------------

extern "C" void kernel_launch(void* const* d_in, const int* in_sizes, int n_in,
                              void* d_out, int out_size, void* d_ws, size_t ws_size,
                              hipStream_t stream) {
  const float* hs        = (const float*)d_in[0];  // [2,2048,1024]
  const float* c_attn_w  = (const float*)d_in[1];  // [1024,3072]
  const float* c_attn_b  = (const float*)d_in[2];  // [3072]
  const float* attn_bias = (const float*)d_in[3];  // [2048,2048]
  const float* c_proj_w  = (const float*)d_in[4];  // [1024,1024]
  const float* c_proj_b  = (const float*)d_in[5];  // [1024]
  float* out = (float*)d_out;  // out(4M) | k(4M) | v(4M)

  uint8_t* ws = (uint8_t*)d_ws;
  u16* hsb    = (u16*)(ws + 0);           // 8MB [4096][1024] bf16 (reused for biasT, 4.3MB)
  u16* wqkvT  = (u16*)(ws + 8388608u);    // 6MB [3072][1024] bf16
  u16* wprojT = (u16*)(ws + 14680064u);   // 2MB [1024][1024] bf16
  u16* q_ws   = (u16*)(ws + 16777216u);   // 8MB [B,H,S,hd] bf16 (q * QSCALE)
  u16* k_ws   = (u16*)(ws + 25165824u);   // 8MB [B,H,S,hd] bf16
  u16* vT_ws  = (u16*)(ws + 33554432u);   // 8MB [B,H,hd,S] bf16 (written by gemm<0>)
  u16* ctx    = (u16*)(ws + 41943040u);   // 8MB [4096][1024] bf16
  u16* biasT  = hsb;                      // overlays hsb after gemm_bt<0>

  prepass_fused<<<8192, 256, 0, stream>>>(hs, hsb, c_attn_w, wqkvT, c_proj_w, wprojT);

  gemm_bt<0><<<dim3(24, 32), 256, 0, stream>>>(hsb, wqkvT, c_attn_b, out,
                                               q_ws, k_ws, vT_ws, 4096, 3072, 1024);

  bias_tile<<<1024, 256, 0, stream>>>(attn_bias, biasT);

  attn_fused<<<dim3(1024), 256, 0, stream>>>(q_ws, k_ws, vT_ws, biasT, ctx);

  gemm_bt<1><<<dim3(8, 32), 256, 0, stream>>>(ctx, wprojT, c_proj_b, out,
                                              (u16*)nullptr, (u16*)nullptr, (u16*)nullptr,
                                              4096, 1024, 1024);
}